// Round 2
// baseline (248.159 us; speedup 1.0000x reference)
//
#include <hip/hip_runtime.h>

#define NPTS 8192
#define DIM 64
#define EPSF 1e-7f

constexpr int TI = 256;               // rows per block == threads per block
constexpr int NJ_CHUNKS = 32;         // split of j-dimension across blocks
constexpr int JCHUNK = NPTS / NJ_CHUNKS;  // 256

// ---------------- kernel 1: squared norms ----------------
__global__ void sq_kernel(const float* __restrict__ x, float* __restrict__ sq) {
    int i = blockIdx.x * blockDim.x + threadIdx.x;
    if (i < NPTS) {
        const float4* r = reinterpret_cast<const float4*>(x + (size_t)i * DIM);
        float s = 0.f;
#pragma unroll
        for (int k = 0; k < DIM / 4; k++) {
            float4 v = r[k];
            s = fmaf(v.x, v.x, s);
            s = fmaf(v.y, v.y, s);
            s = fmaf(v.z, v.z, s);
            s = fmaf(v.w, v.w, s);
        }
        sq[i] = s;
    }
}

// ---------------- kernel 2: all-pairs accumulation ----------------
// Each thread owns one row i (x_i in 64 VGPRs). Block-uniform j loop over a
// JCHUNK slice; x_j loads are uniform-address -> L1 broadcast. Accumulate
// S = sum_{j!=i} exp(-d_ij), T = sum_{pos} -d_ij, P = |pos| locally, then one
// atomicAdd per array per block.
__global__ void __launch_bounds__(TI) pair_kernel(
        const float* __restrict__ x, const int* __restrict__ labels,
        const float* __restrict__ sq,
        float* __restrict__ Sarr, float* __restrict__ Tarr, float* __restrict__ Parr) {
    int i = blockIdx.x * TI + threadIdx.x;
    int j0 = blockIdx.y * JCHUNK;

    float4 xi[DIM / 4];
    const float4* xr = reinterpret_cast<const float4*>(x + (size_t)i * DIM);
#pragma unroll
    for (int k = 0; k < DIM / 4; k++) xi[k] = xr[k];

    float sqi = sq[i];
    float one_m_sqi = 1.0f - sqi;
    int li = labels[i];

    float S = 0.f, T = 0.f, P = 0.f;

    for (int j = j0; j < j0 + JCHUNK; ++j) {
        const float4* xjr = reinterpret_cast<const float4*>(x + (size_t)j * DIM);
        float d0 = 0.f, d1 = 0.f, d2 = 0.f, d3 = 0.f;
#pragma unroll
        for (int k = 0; k < DIM / 4; k++) {
            float4 b = xjr[k];
            d0 = fmaf(xi[k].x, b.x, d0);
            d1 = fmaf(xi[k].y, b.y, d1);
            d2 = fmaf(xi[k].z, b.z, d2);
            d3 = fmaf(xi[k].w, b.w, d3);
        }
        float dot = (d0 + d1) + (d2 + d3);

        float sqj = sq[j];
        float sqdist = fmaxf(sqi + sqj - 2.0f * dot, 0.0f);
        float denom = fmaxf(one_m_sqi * (1.0f - sqj), EPSF);
        float u = fmaxf(2.0f * sqdist * __builtin_amdgcn_rcpf(denom), EPSF);
        // arccosh(1+u) = log(1 + u + sqrt(u*(2+u)))
        float w = u + __builtin_amdgcn_sqrtf(u * (2.0f + u));
        float dist = __logf(1.0f + w);

        if (j != i) {
            S += __expf(-dist);
            if (labels[j] == li) { T -= dist; P += 1.0f; }
        }
    }

    atomicAdd(&Sarr[i], S);
    atomicAdd(&Tarr[i], T);
    atomicAdd(&Parr[i], P);
}

// ---------------- kernel 3: finalize + reduce ----------------
__global__ void finalize_kernel(const float* __restrict__ S, const float* __restrict__ T,
                                const float* __restrict__ P, float* __restrict__ out) {
    __shared__ float red[256];
    float acc = 0.f;
    for (int i = threadIdx.x; i < NPTS; i += 256) {
        acc += __logf(S[i]) - T[i] / P[i];
    }
    red[threadIdx.x] = acc;
    __syncthreads();
    for (int s = 128; s > 0; s >>= 1) {
        if (threadIdx.x < s) red[threadIdx.x] += red[threadIdx.x + s];
        __syncthreads();
    }
    if (threadIdx.x == 0) out[0] = red[0];
}

extern "C" void kernel_launch(void* const* d_in, const int* in_sizes, int n_in,
                              void* d_out, int out_size, void* d_ws, size_t ws_size,
                              hipStream_t stream) {
    const float* x = (const float*)d_in[0];
    const int* labels = (const int*)d_in[1];

    float* sq = (float*)d_ws;
    float* S = sq + NPTS;
    float* T = S + NPTS;
    float* P = T + NPTS;

    // zero S/T/P (covers sq too, harmless)
    (void)hipMemsetAsync(d_ws, 0, 4 * NPTS * sizeof(float), stream);

    sq_kernel<<<NPTS / 256, 256, 0, stream>>>(x, sq);

    dim3 grid(NPTS / TI, NJ_CHUNKS);
    pair_kernel<<<grid, TI, 0, stream>>>(x, labels, sq, S, T, P);

    finalize_kernel<<<1, 256, 0, stream>>>(S, T, P, (float*)d_out);
}

// Round 3
// 247.946 us; speedup vs baseline: 1.0009x; 1.0009x over previous
//
#include <hip/hip_runtime.h>

#define NPTS 8192
#define DIM 64
#define EPSF 1e-7f

constexpr int TI = 256;               // rows per block == threads per block
constexpr int NJ_CHUNKS = 32;         // split of j-dimension across blocks
constexpr int JCHUNK = NPTS / NJ_CHUNKS;  // 256

// ---------------- kernel 1: squared norms ----------------
__global__ void sq_kernel(const float* __restrict__ x, float* __restrict__ sq) {
    int i = blockIdx.x * blockDim.x + threadIdx.x;
    if (i < NPTS) {
        const float4* r = reinterpret_cast<const float4*>(x + (size_t)i * DIM);
        float s = 0.f;
#pragma unroll
        for (int k = 0; k < DIM / 4; k++) {
            float4 v = r[k];
            s = fmaf(v.x, v.x, s);
            s = fmaf(v.y, v.y, s);
            s = fmaf(v.z, v.z, s);
            s = fmaf(v.w, v.w, s);
        }
        sq[i] = s;
    }
}

// ---------------- kernel 2: all-pairs accumulation ----------------
// One thread per row i; x_i held in 64 VGPRs (launch_bounds(256,4) gives a
// 128-VGPR budget so the allocator keeps it resident — with a bare
// launch_bounds(256) it targeted max occupancy, VGPR_Count=40, and re-staged
// xi every iteration: 201us). x_j / sq[j] / labels[j] are block-uniform ->
// SGPR scalar loads (SGPR_Count=96 in R2 confirms).
__global__ void __launch_bounds__(TI, 4) pair_kernel(
        const float* __restrict__ x, const int* __restrict__ labels,
        const float* __restrict__ sq,
        float* __restrict__ Sarr, float* __restrict__ Tarr, float* __restrict__ Parr) {
    int i = blockIdx.x * TI + threadIdx.x;
    int j0 = blockIdx.y * JCHUNK;

    float4 xi[DIM / 4];
    const float4* xr = reinterpret_cast<const float4*>(x + (size_t)i * DIM);
#pragma unroll
    for (int k = 0; k < DIM / 4; k++) xi[k] = xr[k];

    float sqi = sq[i];
    float one_m_sqi = 1.0f - sqi;
    int li = labels[i];

    float S = 0.f, T = 0.f, P = 0.f;

#pragma unroll 2
    for (int j = j0; j < j0 + JCHUNK; ++j) {
        const float4* xjr = reinterpret_cast<const float4*>(x + (size_t)j * DIM);
        float sqj = sq[j];
        int lj = labels[j];
        float d0 = 0.f, d1 = 0.f, d2 = 0.f, d3 = 0.f;
#pragma unroll
        for (int k = 0; k < DIM / 4; k++) {
            float4 b = xjr[k];
            d0 = fmaf(xi[k].x, b.x, d0);
            d1 = fmaf(xi[k].y, b.y, d1);
            d2 = fmaf(xi[k].z, b.z, d2);
            d3 = fmaf(xi[k].w, b.w, d3);
        }
        float dot = (d0 + d1) + (d2 + d3);

        float sqdist = fmaxf(sqi + sqj - 2.0f * dot, 0.0f);
        float denom = fmaxf(one_m_sqi * (1.0f - sqj), EPSF);
        float u = fmaxf(2.0f * sqdist * __builtin_amdgcn_rcpf(denom), EPSF);
        // arccosh(1+u) = log(1 + u + sqrt(u*(2+u)))
        float w = u + __builtin_amdgcn_sqrtf(u * (2.0f + u));
        float dist = __logf(1.0f + w);

        bool diag = (j == i);
        bool pos = (lj == li) && !diag;
        S += diag ? 0.0f : __expf(-dist);
        T -= pos ? dist : 0.0f;
        P += pos ? 1.0f : 0.0f;
    }

    atomicAdd(&Sarr[i], S);
    atomicAdd(&Tarr[i], T);
    atomicAdd(&Parr[i], P);
}

// ---------------- kernel 3: finalize + reduce ----------------
__global__ void finalize_kernel(const float* __restrict__ S, const float* __restrict__ T,
                                const float* __restrict__ P, float* __restrict__ out) {
    __shared__ float red[256];
    float acc = 0.f;
    for (int i = threadIdx.x; i < NPTS; i += 256) {
        acc += __logf(S[i]) - T[i] / P[i];
    }
    red[threadIdx.x] = acc;
    __syncthreads();
    for (int s = 128; s > 0; s >>= 1) {
        if (threadIdx.x < s) red[threadIdx.x] += red[threadIdx.x + s];
        __syncthreads();
    }
    if (threadIdx.x == 0) out[0] = red[0];
}

extern "C" void kernel_launch(void* const* d_in, const int* in_sizes, int n_in,
                              void* d_out, int out_size, void* d_ws, size_t ws_size,
                              hipStream_t stream) {
    const float* x = (const float*)d_in[0];
    const int* labels = (const int*)d_in[1];

    float* sq = (float*)d_ws;
    float* S = sq + NPTS;
    float* T = S + NPTS;
    float* P = T + NPTS;

    // zero S/T/P (covers sq too, harmless)
    (void)hipMemsetAsync(d_ws, 0, 4 * NPTS * sizeof(float), stream);

    sq_kernel<<<NPTS / 256, 256, 0, stream>>>(x, sq);

    dim3 grid(NPTS / TI, NJ_CHUNKS);
    pair_kernel<<<grid, TI, 0, stream>>>(x, labels, sq, S, T, P);

    finalize_kernel<<<1, 256, 0, stream>>>(S, T, P, (float*)d_out);
}

// Round 4
// 155.446 us; speedup vs baseline: 1.5964x; 1.5951x over previous
//
#include <hip/hip_runtime.h>

#define NPTS 8192
#define DIM 64
#define EPSF 1e-7f

typedef unsigned short u16;
typedef __attribute__((ext_vector_type(8))) short bf16x8;   // 8 bf16 (4 VGPRs)
typedef __attribute__((ext_vector_type(8))) unsigned short u16x8;
typedef __attribute__((ext_vector_type(4))) float f32x4;

// ---------------- kernel 1: split x into bf16 hi/lo, compute sq & 1/(1-sq) ----
// 8 threads per row; thread handles 8 consecutive elements (16B stores).
__global__ void prep_kernel(const float* __restrict__ x,
                            u16* __restrict__ hi, u16* __restrict__ lo,
                            float* __restrict__ sq, float* __restrict__ rcpom) {
    int g = blockIdx.x * blockDim.x + threadIdx.x;   // 0 .. NPTS*8-1
    int row = g >> 3, sub = g & 7;
    const float* xp = x + row * DIM + sub * 8;
    float v[8];
    float s = 0.f;
#pragma unroll
    for (int k = 0; k < 8; k++) { v[k] = xp[k]; s = fmaf(v[k], v[k], s); }
    s += __shfl_xor(s, 1);
    s += __shfl_xor(s, 2);
    s += __shfl_xor(s, 4);
    u16x8 h, l;
#pragma unroll
    for (int k = 0; k < 8; k++) {
        unsigned int bits = __float_as_uint(v[k]);
        u16 hb = (u16)(bits >> 16);                       // truncation: hi exact bf16
        float hf = __uint_as_float(((unsigned int)hb) << 16);
        float lf = v[k] - hf;                             // exact in fp32
        u16 lb = (u16)(__float_as_uint(lf) >> 16);
        h[k] = hb; l[k] = lb;
    }
    *(u16x8*)(hi + row * DIM + sub * 8) = h;
    *(u16x8*)(lo + row * DIM + sub * 8) = l;
    if (sub == 0) {
        sq[row] = s;
        rcpom[row] = 1.0f / (1.0f - s);
    }
}

// ---------------- kernel 2: fused MFMA Gram tile + hyperbolic epilogue -------
// Block tile 128(i) x 256(j); 4 waves, each wave 32(i) x 256(j).
// dot = hi.hi + hi.lo + lo.hi via 3 chained mfma_f32_16x16x32_bf16.
// C/D layout: col = lane&15 (j), row = quad*4 + reg (i).
__global__ void __launch_bounds__(256, 3) pair_mfma(
        const u16* __restrict__ hi, const u16* __restrict__ lo,
        const float* __restrict__ sq, const float* __restrict__ rcpom,
        const int* __restrict__ labels,
        float* __restrict__ Sarr, float* __restrict__ Tarr, float* __restrict__ Parr) {
    int tid = threadIdx.x;
    int wave = tid >> 6, lane = tid & 63;
    int quad = lane >> 4, l15 = lane & 15;
    int i0 = blockIdx.x * 128 + wave * 32;   // wave's first i-row
    int j0 = blockIdx.y * 256;

    // A fragments: A[m=l15][k=quad*8+j], rows i0+it*16+l15, resident all j.
    bf16x8 a_hi[2][2], a_lo[2][2];
#pragma unroll
    for (int it = 0; it < 2; it++)
#pragma unroll
        for (int ks = 0; ks < 2; ks++) {
            int off = (i0 + it * 16 + l15) * DIM + ks * 32 + quad * 8;
            a_hi[it][ks] = *(const bf16x8*)(hi + off);
            a_lo[it][ks] = *(const bf16x8*)(lo + off);
        }

    // per-lane i-side scalars for the C-layout rows this lane owns
    float sqi[8], rcpi[8]; int labi[8];
#pragma unroll
    for (int it = 0; it < 2; it++)
#pragma unroll
        for (int r = 0; r < 4; r++) {
            int row = i0 + it * 16 + quad * 4 + r;
            sqi[it * 4 + r] = sq[row];
            rcpi[it * 4 + r] = rcpom[row];
            labi[it * 4 + r] = labels[row];
        }

    float Sx[8], Tx[8], Px[8];
#pragma unroll
    for (int k = 0; k < 8; k++) { Sx[k] = 0.f; Tx[k] = 0.f; Px[k] = 0.f; }

    for (int t = 0; t < 16; t++) {
        int jg = j0 + t * 16 + l15;
        bf16x8 b_hi[2], b_lo[2];
#pragma unroll
        for (int ks = 0; ks < 2; ks++) {
            int off = jg * DIM + ks * 32 + quad * 8;
            b_hi[ks] = *(const bf16x8*)(hi + off);
            b_lo[ks] = *(const bf16x8*)(lo + off);
        }
        float sqj = sq[jg];
        float rcp2j = 2.0f * rcpom[jg];
        int labj = labels[jg];
        int jq = jg - quad * 4;   // diag test: jq == i0 + it*16 + r

#pragma unroll
        for (int it = 0; it < 2; it++) {
            f32x4 acc = {0.f, 0.f, 0.f, 0.f};
#pragma unroll
            for (int ks = 0; ks < 2; ks++) {
                acc = __builtin_amdgcn_mfma_f32_16x16x32_bf16(a_lo[it][ks], b_hi[ks], acc, 0, 0, 0);
                acc = __builtin_amdgcn_mfma_f32_16x16x32_bf16(a_hi[it][ks], b_lo[ks], acc, 0, 0, 0);
                acc = __builtin_amdgcn_mfma_f32_16x16x32_bf16(a_hi[it][ks], b_hi[ks], acc, 0, 0, 0);
            }
#pragma unroll
            for (int r = 0; r < 4; r++) {
                int idx = it * 4 + r;
                float dot = acc[r];
                float sqd = fmaf(-2.f, dot, sqi[idx] + sqj);
                sqd = fmaxf(sqd, 0.f);
                float u = (sqd * rcpi[idx]) * rcp2j;      // 2*sqd/denom
                u = fmaxf(u, EPSF);
                float srt = __builtin_amdgcn_sqrtf(fmaf(u, u, 2.f * u));  // sqrt(u(2+u))
                float w1 = 1.f + u + srt;                 // exp(dist)
                float st = __builtin_amdgcn_rcpf(w1);     // exp(-dist), exact identity
                float dist = __logf(w1);                  // arccosh(1+u)
                bool diag = (jq == i0 + it * 16 + r);
                bool pos = (labj == labi[idx]) && !diag;
                Sx[idx] += diag ? 0.f : st;
                Tx[idx] += pos ? dist : 0.f;
                Px[idx] += pos ? 1.f : 0.f;
            }
        }
    }

    // reduce across the 16 columns (lanes sharing quad hold the same rows)
#pragma unroll
    for (int idx = 0; idx < 8; idx++) {
#pragma unroll
        for (int m = 1; m < 16; m <<= 1) {
            Sx[idx] += __shfl_xor(Sx[idx], m);
            Tx[idx] += __shfl_xor(Tx[idx], m);
            Px[idx] += __shfl_xor(Px[idx], m);
        }
    }
    if (l15 == 0) {
#pragma unroll
        for (int it = 0; it < 2; it++)
#pragma unroll
            for (int r = 0; r < 4; r++) {
                int row = i0 + it * 16 + quad * 4 + r;
                atomicAdd(&Sarr[row], Sx[it * 4 + r]);
                atomicAdd(&Tarr[row], Tx[it * 4 + r]);
                atomicAdd(&Parr[row], Px[it * 4 + r]);
            }
    }
}

// ---------------- kernel 3: finalize + reduce --------------------------------
// loss_i = ln(S_i) + T_i/P_i   (T accumulated as +dist over positives)
__global__ void finalize_kernel(const float* __restrict__ S, const float* __restrict__ T,
                                const float* __restrict__ P, float* __restrict__ out) {
    __shared__ float red[256];
    float acc = 0.f;
    for (int i = threadIdx.x; i < NPTS; i += 256) {
        acc += __logf(S[i]) + T[i] / P[i];
    }
    red[threadIdx.x] = acc;
    __syncthreads();
    for (int s = 128; s > 0; s >>= 1) {
        if (threadIdx.x < s) red[threadIdx.x] += red[threadIdx.x + s];
        __syncthreads();
    }
    if (threadIdx.x == 0) out[0] = red[0];
}

extern "C" void kernel_launch(void* const* d_in, const int* in_sizes, int n_in,
                              void* d_out, int out_size, void* d_ws, size_t ws_size,
                              hipStream_t stream) {
    const float* x = (const float*)d_in[0];
    const int* labels = (const int*)d_in[1];

    u16* hi = (u16*)d_ws;                 // NPTS*DIM
    u16* lo = hi + NPTS * DIM;            // NPTS*DIM
    float* sq = (float*)(lo + NPTS * DIM);
    float* rcpom = sq + NPTS;
    float* S = rcpom + NPTS;
    float* T = S + NPTS;
    float* P = T + NPTS;

    (void)hipMemsetAsync(S, 0, 3 * NPTS * sizeof(float), stream);

    prep_kernel<<<(NPTS * 8) / 256, 256, 0, stream>>>(x, hi, lo, sq, rcpom);

    dim3 grid(NPTS / 128, NPTS / 256);
    pair_mfma<<<grid, 256, 0, stream>>>(hi, lo, sq, rcpom, labels, S, T, P);

    finalize_kernel<<<1, 256, 0, stream>>>(S, T, P, (float*)d_out);
}

// Round 5
// 144.407 us; speedup vs baseline: 1.7185x; 1.0764x over previous
//
#include <hip/hip_runtime.h>

#define NPTS 8192
#define DIM 64
#define EPSF 1e-7f
#define LN2F 0.69314718055994531f

typedef unsigned short u16;
typedef __attribute__((ext_vector_type(8))) short bf16x8;   // 8 bf16 (4 VGPRs)
typedef __attribute__((ext_vector_type(8))) unsigned short u16x8;
typedef __attribute__((ext_vector_type(4))) float f32x4;

// ---------------- kernel 1: split x into bf16 hi/lo, compute sq & 1/(1-sq) ----
__global__ void prep_kernel(const float* __restrict__ x,
                            u16* __restrict__ hi, u16* __restrict__ lo,
                            float* __restrict__ sq, float* __restrict__ rcpom) {
    int g = blockIdx.x * blockDim.x + threadIdx.x;   // 0 .. NPTS*8-1
    int row = g >> 3, sub = g & 7;
    const float* xp = x + row * DIM + sub * 8;
    float v[8];
    float s = 0.f;
#pragma unroll
    for (int k = 0; k < 8; k++) { v[k] = xp[k]; s = fmaf(v[k], v[k], s); }
    s += __shfl_xor(s, 1);
    s += __shfl_xor(s, 2);
    s += __shfl_xor(s, 4);
    u16x8 h, l;
#pragma unroll
    for (int k = 0; k < 8; k++) {
        unsigned int bits = __float_as_uint(v[k]);
        u16 hb = (u16)(bits >> 16);                       // truncation: hi exact bf16
        float hf = __uint_as_float(((unsigned int)hb) << 16);
        float lf = v[k] - hf;                             // exact in fp32
        u16 lb = (u16)(__float_as_uint(lf) >> 16);
        h[k] = hb; l[k] = lb;
    }
    *(u16x8*)(hi + row * DIM + sub * 8) = h;
    *(u16x8*)(lo + row * DIM + sub * 8) = l;
    if (sub == 0) {
        sq[row] = s;
        rcpom[row] = 1.0f / (1.0f - s);
    }
}

// ---------------- kernel 1b: label histogram (for analytic P) ----------------
__global__ void count_kernel(const int* __restrict__ labels, int* __restrict__ cnt) {
    __shared__ int c[16 * 16];                 // 16 replicas to spread contention
    for (int k = threadIdx.x; k < 256; k += 256) c[k] = 0;
    __syncthreads();
    int slice = (threadIdx.x & 15) * 16;
    for (int i = threadIdx.x; i < NPTS; i += 256)
        atomicAdd(&c[slice + labels[i]], 1);
    __syncthreads();
    if (threadIdx.x < 16) {
        int s = 0;
#pragma unroll
        for (int rrep = 0; rrep < 16; rrep++) s += c[rrep * 16 + threadIdx.x];
        cnt[threadIdx.x] = s;
    }
}

// ---------------- kernel 2: fused MFMA Gram tile + hyperbolic epilogue -------
// Block tile 128(i) x 256(j); 4 waves, wave tile 32(i) x 256(j).
// dot split: hi.hi + hi.lo + lo.hi (bf16), C-init = -0.5(sqi+sqj) folded in.
// Epilogue per pair (no diag test, no P, no rcp):
//   u   = max(D * rcpi * (-4 rcpj), EPS)        (== reference clamp semantics)
//   srt = sqrt(u*(2+u));  st = (1+u)-srt = exp(-d);  l2 = log2((1+u)+srt) = d/ln2
__global__ void __launch_bounds__(256, 3) pair_mfma(
        const u16* __restrict__ hi, const u16* __restrict__ lo,
        const float* __restrict__ sq, const float* __restrict__ rcpom,
        const int* __restrict__ labels,
        float* __restrict__ Sarr, float* __restrict__ Tarr) {
    int tid = threadIdx.x;
    int wave = tid >> 6, lane = tid & 63;
    int quad = lane >> 4, l15 = lane & 15;
    int i0 = blockIdx.x * 128 + wave * 32;
    int j0 = blockIdx.y * 256;

    bf16x8 a_hi[2][2], a_lo[2][2];
#pragma unroll
    for (int it = 0; it < 2; it++)
#pragma unroll
        for (int ks = 0; ks < 2; ks++) {
            int off = (i0 + it * 16 + l15) * DIM + ks * 32 + quad * 8;
            a_hi[it][ks] = *(const bf16x8*)(hi + off);
            a_lo[it][ks] = *(const bf16x8*)(lo + off);
        }

    float hsqi[8], rcpi[8]; int labi[8];
#pragma unroll
    for (int it = 0; it < 2; it++)
#pragma unroll
        for (int r = 0; r < 4; r++) {
            int row = i0 + it * 16 + quad * 4 + r;
            hsqi[it * 4 + r] = -0.5f * sq[row];
            rcpi[it * 4 + r] = rcpom[row];
            labi[it * 4 + r] = labels[row];
        }

    float Sx[8], Tx[8];
#pragma unroll
    for (int k = 0; k < 8; k++) { Sx[k] = 0.f; Tx[k] = 0.f; }

    for (int t = 0; t < 16; t++) {
        int jg = j0 + t * 16 + l15;
        bf16x8 b_hi[2], b_lo[2];
#pragma unroll
        for (int ks = 0; ks < 2; ks++) {
            int off = jg * DIM + ks * 32 + quad * 8;
            b_hi[ks] = *(const bf16x8*)(hi + off);
            b_lo[ks] = *(const bf16x8*)(lo + off);
        }
        float hsqj = -0.5f * sq[jg];
        float mj = -4.0f * rcpom[jg];
        int labj = labels[jg];

#pragma unroll
        for (int it = 0; it < 2; it++) {
            f32x4 acc;
#pragma unroll
            for (int r = 0; r < 4; r++) acc[r] = hsqi[it * 4 + r] + hsqj;
#pragma unroll
            for (int ks = 0; ks < 2; ks++) {
                acc = __builtin_amdgcn_mfma_f32_16x16x32_bf16(a_lo[it][ks], b_hi[ks], acc, 0, 0, 0);
                acc = __builtin_amdgcn_mfma_f32_16x16x32_bf16(a_hi[it][ks], b_lo[ks], acc, 0, 0, 0);
                acc = __builtin_amdgcn_mfma_f32_16x16x32_bf16(a_hi[it][ks], b_hi[ks], acc, 0, 0, 0);
            }
#pragma unroll
            for (int r = 0; r < 4; r++) {
                int idx = it * 4 + r;
                float u = fmaxf(acc[r] * rcpi[idx] * mj, EPSF);
                float srt = __builtin_amdgcn_sqrtf(fmaf(u, u, u + u));
                float opu = 1.0f + u;
                Sx[idx] += opu - srt;                       // exp(-d)
                float l2 = __builtin_amdgcn_logf(opu + srt); // d / ln2
                Tx[idx] += (labj == labi[idx]) ? l2 : 0.0f;
            }
        }
    }

    // reduce across the 16 columns (lanes within a quad hold the same rows)
#pragma unroll
    for (int idx = 0; idx < 8; idx++) {
#pragma unroll
        for (int m = 1; m < 16; m <<= 1) {
            Sx[idx] += __shfl_xor(Sx[idx], m);
            Tx[idx] += __shfl_xor(Tx[idx], m);
        }
    }
    if (l15 == 0) {
#pragma unroll
        for (int it = 0; it < 2; it++)
#pragma unroll
            for (int r = 0; r < 4; r++) {
                int row = i0 + it * 16 + quad * 4 + r;
                atomicAdd(&Sarr[row], Sx[it * 4 + r]);
                atomicAdd(&Tarr[row], Tx[it * 4 + r]);
            }
    }
}

// ---------------- kernel 3: finalize (parallel) ------------------------------
// loss_i = ln(S_i - st_self) + ln2*(T_i - l2_self)/P_i ;  P_i = cnt[lab_i]-1
__global__ void finalize_kernel(const float* __restrict__ S, const float* __restrict__ T,
                                const int* __restrict__ cnt, const int* __restrict__ labels,
                                float* __restrict__ out) {
    __shared__ float red[256];
    int i = blockIdx.x * 256 + threadIdx.x;
    float s0 = __builtin_amdgcn_sqrtf(EPSF * (2.0f + EPSF));
    float st0 = 1.0f + EPSF - s0;                       // self exp(-d) term
    float l20 = __builtin_amdgcn_logf(1.0f + EPSF + s0); // self log2 term
    float p = (float)(cnt[labels[i]] - 1);
    float loss = __logf(S[i] - st0) + (T[i] - l20) * LN2F / p;
    red[threadIdx.x] = loss;
    __syncthreads();
    for (int s = 128; s > 0; s >>= 1) {
        if (threadIdx.x < s) red[threadIdx.x] += red[threadIdx.x + s];
        __syncthreads();
    }
    if (threadIdx.x == 0) atomicAdd(out, red[0]);
}

extern "C" void kernel_launch(void* const* d_in, const int* in_sizes, int n_in,
                              void* d_out, int out_size, void* d_ws, size_t ws_size,
                              hipStream_t stream) {
    const float* x = (const float*)d_in[0];
    const int* labels = (const int*)d_in[1];

    u16* hi = (u16*)d_ws;                 // NPTS*DIM u16
    u16* lo = hi + NPTS * DIM;            // NPTS*DIM u16
    float* sq = (float*)(lo + NPTS * DIM);
    float* rcpom = sq + NPTS;
    float* S = rcpom + NPTS;
    float* T = S + NPTS;
    int* cnt = (int*)(T + NPTS);

    (void)hipMemsetAsync(d_out, 0, sizeof(float), stream);
    (void)hipMemsetAsync(S, 0, 2 * NPTS * sizeof(float), stream);

    prep_kernel<<<(NPTS * 8) / 256, 256, 0, stream>>>(x, hi, lo, sq, rcpom);
    count_kernel<<<1, 256, 0, stream>>>(labels, cnt);

    dim3 grid(NPTS / 128, NPTS / 256);
    pair_mfma<<<grid, 256, 0, stream>>>(hi, lo, sq, rcpom, labels, S, T);

    finalize_kernel<<<NPTS / 256, 256, 0, stream>>>(S, T, cnt, labels, (float*)d_out);
}